// Round 5
// baseline (166.785 us; speedup 1.0000x reference)
//
#include <hip/hip_runtime.h>
#include <math.h>

#define M_SPATIAL 2097152  // 128^3

typedef float f32x2 __attribute__((ext_vector_type(2)));

__device__ __forceinline__ float wave_redf(float v) {
#pragma unroll
  for (int o = 32; o > 0; o >>= 1) v += __shfl_down(v, o, 64);
  return v;
}
__device__ __forceinline__ double wave_redd(double v) {
#pragma unroll
  for (int o = 32; o > 0; o >>= 1) v += __shfl_down(v, o, 64);
  return v;
}
// Forced VOP3P packed fma: two independent IEEE f32 fmas in one issue slot.
__device__ __forceinline__ f32x2 pk_fma(f32x2 a, f32x2 b, f32x2 c) {
  f32x2 d;
  asm("v_pk_fma_f32 %0, %1, %2, %3" : "=v"(d) : "v"(a), "v"(b), "v"(c));
  return d;
}
// Forced 3-input min (VOP3 v_min3_f32); exact, order-independent.
__device__ __forceinline__ float min3f(float a, float b, float c) {
  float d;
  asm("v_min3_f32 %0, %1, %2, %3" : "=v"(d) : "v"(a), "v"(b), "v"(c));
  return d;
}

// part layout (doubles):
// [0..1023]=ce  [1024..2047]=p  [2048..3071]=pt  [3072..4095]=t
// [4096..4351]=dist (256 kCD blocks)

// ---------------------------------------------------------------------------
// kAB: X-axis EDT (blocked parallel scan) FUSED with CE + dice partials.
// xc is already batch-offset -> spatial-only index sp (round-2 OOB lesson).
// Writes h = gX + y^2 for the Y pass.
// ---------------------------------------------------------------------------
__global__ __launch_bounds__(256) void kAB(const int* __restrict__ y,
                                           const float* __restrict__ outputs,
                                           float* __restrict__ g,
                                           double* __restrict__ part) {
  int blk = blockIdx.x;            // b*512 + yy*4 + zq
  int b  = blk >> 9;
  int yy = (blk >> 2) & 127;
  int zq = blk & 3;
  int t  = threadIdx.x;
  int c  = t >> 5;                 // x-chunk 0..7 (16 x each)
  int zl = t & 31;                 // z within 32-chunk
  int x0 = c * 16;
  size_t sp   = (size_t)yy * 128 + (size_t)zq * 32 + zl;    // spatial-only
  size_t base = (size_t)b * M_SPATIAL + sp;                 // batch + spatial
  const float* xc = outputs + (size_t)(b * 2 + 1) * M_SPATIAL;

  int yb[16];
  float xv[16];
#pragma unroll
  for (int k = 0; k < 16; ++k) yb[k] = y[base + (size_t)(x0 + k) * 16384];
#pragma unroll
  for (int k = 0; k < 16; ++k) xv[k] = xc[sp + (size_t)(x0 + k) * 16384];

  int lastE = -200, nextE = 400;
#pragma unroll
  for (int k = 0; k < 16; ++k) lastE = (yb[k] == 1) ? lastE : (x0 + k);
#pragma unroll
  for (int k = 15; k >= 0; --k) nextE = (yb[k] == 1) ? nextE : (x0 + k);

  __shared__ int lE[8][32];
  __shared__ int nE[8][32];
  lE[c][zl] = lastE;
  nE[c][zl] = nextE;
  __syncthreads();

  int carryL = -200, carryN = 400;
#pragma unroll
  for (int q = 0; q < 7; ++q) {
    if (q < c)     carryL = max(carryL, lE[q][zl]);
    if (q + 1 > c) carryN = min(carryN, nE[q + 1][zl]);
  }

  float yy2f = (float)(yy * yy);
  float hinf = 1000000.f + yy2f;

  int df[16];
  int ll = carryL;
#pragma unroll
  for (int k = 0; k < 16; ++k) {
    ll = (yb[k] == 1) ? ll : (x0 + k);
    df[k] = min(x0 + k - ll, 200);
  }
  float ov[16];
  int nn = carryN;
#pragma unroll
  for (int k = 15; k >= 0; --k) {
    nn = (yb[k] == 1) ? nn : (x0 + k);
    int m = min(df[k], min(nn - (x0 + k), 200));
    ov[k] = (m >= 128) ? hinf : ((float)(m * m) + yy2f);
  }
#pragma unroll
  for (int k = 0; k < 16; ++k) g[base + (size_t)(x0 + k) * 16384] = ov[k];

  float ce = 0.f, ps = 0.f, pts = 0.f, tsum = 0.f;
#pragma unroll
  for (int k = 0; k < 16; ++k) {
    float tt = (yb[k] == 1) ? 1.0f : 0.0f;
    float xx = xv[k];
    ce += fmaxf(xx, 0.0f) - xx * tt + log1pf(expf(-fabsf(xx)));
    float p = 1.0f / (1.0f + expf(-xx));
    ps += p; pts += p * tt; tsum += tt;
  }
  float r0 = wave_redf(ce), r1 = wave_redf(ps), r2 = wave_redf(pts), r3 = wave_redf(tsum);
  __shared__ float sm[4][4];
  int lane = t & 63, w = t >> 6;
  if (lane == 0) { sm[w][0] = r0; sm[w][1] = r1; sm[w][2] = r2; sm[w][3] = r3; }
  __syncthreads();
  if (t == 0) {
    part[blk]        = (double)(sm[0][0] + sm[1][0] + sm[2][0] + sm[3][0]);
    part[1024 + blk] = (double)(sm[0][1] + sm[1][1] + sm[2][1] + sm[3][1]);
    part[2048 + blk] = (double)(sm[0][2] + sm[1][2] + sm[2][2] + sm[3][2]);
    part[3072 + blk] = (double)(sm[0][3] + sm[1][3] + sm[2][3] + sm[3][3]);
  }
}

// ---------------------------------------------------------------------------
// kCD: Y pass + Z pass + dist loss, one block per (b,x) slab.
// Geometry reverted to the measured-best round-3 config (512 thr, 32
// outputs/thread, 91% VALUBusy): the only lever left is instr/(j,i).
// Inner step FORCED via inline asm: 1 v_pk_fma_f32 (2 fmas) + 1 v_min3_f32
// per (2 parabolas x output) = 1.0 VALU per (j,i), vs ~3 effective before.
// mc2[32] duplicated-constant pairs = 64 VGPR (deliberate; peak ~150 < 256
// cap at 2 waves/SIMD). Bit-exact: pk_fma == two scalar IEEE fmas.
// ---------------------------------------------------------------------------
__global__ __launch_bounds__(512) void kCD(const float* __restrict__ g,
                                           const float* __restrict__ od,
                                           double* __restrict__ part) {
  __shared__ float sbuf[128 * 132];   // 67.6 KB, reused across passes
  __shared__ float sred[8];
  int blk = blockIdx.x;               // b*128 + x
  int b = blk >> 7, xx = blk & 127;
  int t = threadIdx.x;
  size_t rb = (size_t)b * M_SPATIAL + (size_t)xx * 16384;

  // od prefetch (Z-pass operand) issued first; lands during the Y pass.
  int yl = t >> 2, izb = (t & 3) * 32;
  size_t odb = (size_t)(2 * b + 1) * M_SPATIAL + (size_t)xx * 16384 +
               (size_t)yl * 128 + (size_t)izb;
  const float4* o4 = (const float4*)(od + odb);
  float4 ovv[8];
#pragma unroll
  for (int r = 0; r < 8; ++r) ovv[r] = o4[r];

  // Stage the slab: 4096 float4, coalesced (2-way LDS aliasing max = free).
  const float4* g4 = (const float4*)(g + rb);
#pragma unroll
  for (int r = 0; r < 8; ++r) {
    int i4 = t + r * 512;             // 0..4095
    float4 v = g4[i4];
    int flat = i4 * 4;
    int ys = flat >> 7, zs = flat & 127;
    *(float4*)&sbuf[ys * 132 + zs] = v;
  }
  __syncthreads();

  // ---- Y pass: z = t&127 fixed, 32 i's.
  {
    int z = t & 127, ibase = (t >> 7) * 32;
    float zq = (float)(z * z);
    float best[32];
    f32x2 mc2[32];
#pragma unroll
    for (int k = 0; k < 32; ++k) {
      best[k] = 3.0e38f;
      float m = -2.0f * (float)(ibase + k);
      mc2[k] = (f32x2){m, m};
    }
    f32x2 jv = {0.0f, 1.0f};
#pragma unroll 4
    for (int j = 0; j < 128; j += 2) {
      f32x2 hv = {sbuf[j * 132 + z], sbuf[(j + 1) * 132 + z]};
#pragma unroll
      for (int k = 0; k < 32; ++k) {
        f32x2 v = pk_fma(mc2[k], jv, hv);
        best[k] = min3f(v.x, v.y, best[k]);
      }
      jv += (f32x2){2.0f, 2.0f};
    }
    __syncthreads();                  // everyone done READING sbuf
#pragma unroll
    for (int k = 0; k < 32; ++k) {
      int i = ibase + k;
      float dY = (float)(i * i) + best[k];   // exact int
      sbuf[z * 129 + i] = dY + zq;           // h for Z pass, transposed layout
    }
  }
  __syncthreads();

  // ---- Z pass + dist loss: y = t>>2 fixed, 32 i(z)'s.
  {
    float best[32];
    f32x2 mc2[32];
#pragma unroll
    for (int k = 0; k < 32; ++k) {
      best[k] = 3.0e38f;
      float m = -2.0f * (float)(izb + k);
      mc2[k] = (f32x2){m, m};
    }
    f32x2 jv = {0.0f, 1.0f};
#pragma unroll 4
    for (int j = 0; j < 128; j += 2) {
      f32x2 hv = {sbuf[j * 129 + yl], sbuf[(j + 1) * 129 + yl]};
#pragma unroll
      for (int k = 0; k < 32; ++k) {
        f32x2 v = pk_fma(mc2[k], jv, hv);
        best[k] = min3f(v.x, v.y, best[k]);
      }
      jv += (f32x2){2.0f, 2.0f};
    }
    const float* of = (const float*)ovv;
    float dist = 0.f;
#pragma unroll
    for (int k = 0; k < 32; ++k) {
      int i = izb + k;
      float dv = (float)(i * i) + best[k];   // exact squared EDT
      if (dv > 0.f) dist += fabsf(of[k] - sqrtf(dv));
    }
    float r = wave_redf(dist);
    int lane = t & 63, w = t >> 6;
    if (lane == 0) sred[w] = r;
  }
  __syncthreads();
  if (t == 0) {
    float s = 0.f;
#pragma unroll
    for (int q = 0; q < 8; ++q) s += sred[q];
    part[4096 + blk] = (double)s;
  }
}

// ---------------------------------------------------------------------------
// k_final: reduce partials (1024 ce/dice slots, 256 dist slots) -> loss.
// ---------------------------------------------------------------------------
__global__ __launch_bounds__(256) void k_final(const double* __restrict__ part,
                                               const float* __restrict__ wptr,
                                               float* __restrict__ out) {
  int i = threadIdx.x;
  double ce  = part[i] + part[i + 256] + part[i + 512] + part[i + 768];
  double p0  = part[1024 + i] + part[1024 + i + 256];
  double p1  = part[1536 + i] + part[1536 + i + 256];
  double pt0 = part[2048 + i] + part[2048 + i + 256];
  double pt1 = part[2560 + i] + part[2560 + i + 256];
  double t0  = part[3072 + i] + part[3072 + i + 256];
  double t1  = part[3584 + i] + part[3584 + i + 256];
  double ds  = part[4096 + i];   // 256 kCD blocks, one slot per thread

  ce = wave_redd(ce); p0 = wave_redd(p0); p1 = wave_redd(p1);
  pt0 = wave_redd(pt0); pt1 = wave_redd(pt1);
  t0 = wave_redd(t0); t1 = wave_redd(t1); ds = wave_redd(ds);

  __shared__ double sm[4][8];
  int lane = threadIdx.x & 63, w = threadIdx.x >> 6;
  if (lane == 0) {
    sm[w][0] = ce; sm[w][1] = p0; sm[w][2] = p1; sm[w][3] = pt0;
    sm[w][4] = pt1; sm[w][5] = t0; sm[w][6] = t1; sm[w][7] = ds;
  }
  __syncthreads();
  if (threadIdx.x == 0) {
    double a[8];
    for (int q = 0; q < 8; ++q) a[q] = sm[0][q] + sm[1][q] + sm[2][q] + sm[3][q];
    double cem = a[0] / 4194304.0;
    double dice0 = (2.0 * a[3] + 1.0) / (a[1] + a[5] + 1.0);
    double dice1 = (2.0 * a[4] + 1.0) / (a[2] + a[6] + 1.0);
    double ldice = 1.0 - 0.5 * (dice0 + dice1);
    double msum = a[5] + a[6];
    double ldist = (msum == 0.0) ? 0.0 : a[7] / fmax(msum, 1e-12);
    out[0] = (float)(cem + ldice + (double)wptr[0] * ldist);
  }
}

extern "C" void kernel_launch(void* const* d_in, const int* in_sizes, int n_in,
                              void* d_out, int out_size, void* d_ws, size_t ws_size,
                              hipStream_t stream) {
  const float* outputs      = (const float*)d_in[0];
  const float* outputs_dist = (const float*)d_in[1];
  const int*   y            = (const int*)d_in[2];
  const float* wptr         = (const float*)d_in[3];
  float* out = (float*)d_out;

  double* part = (double*)d_ws;                    // 4352 doubles
  float* g = (float*)((char*)d_ws + 65536);        // 16 MiB h field

  kAB<<<1024, 256, 0, stream>>>(y, outputs, g, part);      // X scan + CE/dice
  kCD<<<256, 512, 0, stream>>>(g, outputs_dist, part);     // Y+Z EDT + dist
  k_final<<<1, 256, 0, stream>>>(part, wptr, out);
}

// Round 6
// 165.228 us; speedup vs baseline: 1.0094x; 1.0094x over previous
//
#include <hip/hip_runtime.h>
#include <math.h>

#define M_SPATIAL 2097152  // 128^3

typedef float f32x2 __attribute__((ext_vector_type(2)));

__device__ __forceinline__ float wave_redf(float v) {
#pragma unroll
  for (int o = 32; o > 0; o >>= 1) v += __shfl_down(v, o, 64);
  return v;
}
__device__ __forceinline__ double wave_redd(double v) {
#pragma unroll
  for (int o = 32; o > 0; o >>= 1) v += __shfl_down(v, o, 64);
  return v;
}
// Forced VOP3P packed fma: two independent IEEE f32 fmas in one issue slot.
__device__ __forceinline__ f32x2 pk_fma(f32x2 a, f32x2 b, f32x2 c) {
  f32x2 d;
  asm("v_pk_fma_f32 %0, %1, %2, %3" : "=v"(d) : "v"(a), "v"(b), "v"(c));
  return d;
}
// Forced 3-input min (VOP3 v_min3_f32); exact, order-independent.
__device__ __forceinline__ float min3f(float a, float b, float c) {
  float d;
  asm("v_min3_f32 %0, %1, %2, %3" : "=v"(d) : "v"(a), "v"(b), "v"(c));
  return d;
}

// part layout (doubles):
// [0..1023]=ce  [1024..2047]=p  [2048..3071]=pt  [3072..4095]=t
// [4096..4351]=dist (256 kCD blocks)

// ---------------------------------------------------------------------------
// kAB: X-axis EDT (blocked parallel scan) FUSED with CE + dice partials.
// xc is already batch-offset -> spatial-only index sp (round-2 OOB lesson).
// Writes h = gX + y^2 for the Y pass.
// ---------------------------------------------------------------------------
__global__ __launch_bounds__(256) void kAB(const int* __restrict__ y,
                                           const float* __restrict__ outputs,
                                           float* __restrict__ g,
                                           double* __restrict__ part) {
  int blk = blockIdx.x;            // b*512 + yy*4 + zq
  int b  = blk >> 9;
  int yy = (blk >> 2) & 127;
  int zq = blk & 3;
  int t  = threadIdx.x;
  int c  = t >> 5;                 // x-chunk 0..7 (16 x each)
  int zl = t & 31;                 // z within 32-chunk
  int x0 = c * 16;
  size_t sp   = (size_t)yy * 128 + (size_t)zq * 32 + zl;    // spatial-only
  size_t base = (size_t)b * M_SPATIAL + sp;                 // batch + spatial
  const float* xc = outputs + (size_t)(b * 2 + 1) * M_SPATIAL;

  int yb[16];
  float xv[16];
#pragma unroll
  for (int k = 0; k < 16; ++k) yb[k] = y[base + (size_t)(x0 + k) * 16384];
#pragma unroll
  for (int k = 0; k < 16; ++k) xv[k] = xc[sp + (size_t)(x0 + k) * 16384];

  int lastE = -200, nextE = 400;
#pragma unroll
  for (int k = 0; k < 16; ++k) lastE = (yb[k] == 1) ? lastE : (x0 + k);
#pragma unroll
  for (int k = 15; k >= 0; --k) nextE = (yb[k] == 1) ? nextE : (x0 + k);

  __shared__ int lE[8][32];
  __shared__ int nE[8][32];
  lE[c][zl] = lastE;
  nE[c][zl] = nextE;
  __syncthreads();

  int carryL = -200, carryN = 400;
#pragma unroll
  for (int q = 0; q < 7; ++q) {
    if (q < c)     carryL = max(carryL, lE[q][zl]);
    if (q + 1 > c) carryN = min(carryN, nE[q + 1][zl]);
  }

  float yy2f = (float)(yy * yy);
  float hinf = 1000000.f + yy2f;

  int df[16];
  int ll = carryL;
#pragma unroll
  for (int k = 0; k < 16; ++k) {
    ll = (yb[k] == 1) ? ll : (x0 + k);
    df[k] = min(x0 + k - ll, 200);
  }
  float ov[16];
  int nn = carryN;
#pragma unroll
  for (int k = 15; k >= 0; --k) {
    nn = (yb[k] == 1) ? nn : (x0 + k);
    int m = min(df[k], min(nn - (x0 + k), 200));
    ov[k] = (m >= 128) ? hinf : ((float)(m * m) + yy2f);
  }
#pragma unroll
  for (int k = 0; k < 16; ++k) g[base + (size_t)(x0 + k) * 16384] = ov[k];

  float ce = 0.f, ps = 0.f, pts = 0.f, tsum = 0.f;
#pragma unroll
  for (int k = 0; k < 16; ++k) {
    float tt = (yb[k] == 1) ? 1.0f : 0.0f;
    float xx = xv[k];
    ce += fmaxf(xx, 0.0f) - xx * tt + log1pf(expf(-fabsf(xx)));
    float p = 1.0f / (1.0f + expf(-xx));
    ps += p; pts += p * tt; tsum += tt;
  }
  float r0 = wave_redf(ce), r1 = wave_redf(ps), r2 = wave_redf(pts), r3 = wave_redf(tsum);
  __shared__ float sm[4][4];
  int lane = t & 63, w = t >> 6;
  if (lane == 0) { sm[w][0] = r0; sm[w][1] = r1; sm[w][2] = r2; sm[w][3] = r3; }
  __syncthreads();
  if (t == 0) {
    part[blk]        = (double)(sm[0][0] + sm[1][0] + sm[2][0] + sm[3][0]);
    part[1024 + blk] = (double)(sm[0][1] + sm[1][1] + sm[2][1] + sm[3][1]);
    part[2048 + blk] = (double)(sm[0][2] + sm[1][2] + sm[2][2] + sm[3][2]);
    part[3072 + blk] = (double)(sm[0][3] + sm[1][3] + sm[2][3] + sm[3][3]);
  }
}

// ---------------------------------------------------------------------------
// kCD: Y pass + Z pass + dist loss, one block per (b,x) slab.
// Round-5 lesson: pk_fma density was right, but the default VGPR target
// (128) forced scratch spills (WRITE_SIZE 8KB->4MB, VALUBusy 54%).
// Fixes: (a) __launch_bounds__(512, 1) -> 256-VGPR cap, no spill (occupancy
// stays 2 waves/SIMD = round-3 level, fine for an issue-bound kernel);
// (b) od prefetch moved AFTER the Y pass so its 32 VGPRs aren't live
// through the Y j-loop (peak ~110 Y / ~145 Z).
// Inner step: 1 v_pk_fma_f32 + 1 v_min3_f32 per (2 parabolas x output).
// Bit-exact: pk_fma == two scalar IEEE fmas; min3 order-independent.
// ---------------------------------------------------------------------------
__global__ __launch_bounds__(512, 1) void kCD(const float* __restrict__ g,
                                              const float* __restrict__ od,
                                              double* __restrict__ part) {
  __shared__ float sbuf[128 * 132];   // 67.6 KB, reused across passes
  __shared__ float sred[8];
  int blk = blockIdx.x;               // b*128 + x
  int b = blk >> 7, xx = blk & 127;
  int t = threadIdx.x;
  size_t rb = (size_t)b * M_SPATIAL + (size_t)xx * 16384;

  // Stage the slab: 4096 float4, coalesced (2-way LDS aliasing max = free).
  const float4* g4 = (const float4*)(g + rb);
#pragma unroll
  for (int r = 0; r < 8; ++r) {
    int i4 = t + r * 512;             // 0..4095
    float4 v = g4[i4];
    int flat = i4 * 4;
    int ys = flat >> 7, zs = flat & 127;
    *(float4*)&sbuf[ys * 132 + zs] = v;
  }
  __syncthreads();

  // ---- Y pass: z = t&127 fixed, 32 i's.
  {
    int z = t & 127, ibase = (t >> 7) * 32;
    float zq = (float)(z * z);
    float best[32];
    f32x2 mc2[32];
#pragma unroll
    for (int k = 0; k < 32; ++k) {
      best[k] = 3.0e38f;
      float m = -2.0f * (float)(ibase + k);
      mc2[k] = (f32x2){m, m};
    }
    f32x2 jv = {0.0f, 1.0f};
#pragma unroll 4
    for (int j = 0; j < 128; j += 2) {
      f32x2 hv = {sbuf[j * 132 + z], sbuf[(j + 1) * 132 + z]};
#pragma unroll
      for (int k = 0; k < 32; ++k) {
        f32x2 v = pk_fma(mc2[k], jv, hv);
        best[k] = min3f(v.x, v.y, best[k]);
      }
      jv += (f32x2){2.0f, 2.0f};
    }
    __syncthreads();                  // everyone done READING sbuf
#pragma unroll
    for (int k = 0; k < 32; ++k) {
      int i = ibase + k;
      float dY = (float)(i * i) + best[k];   // exact int
      sbuf[z * 129 + i] = dY + zq;           // h for Z pass, transposed layout
    }
  }
  __syncthreads();

  // ---- Z pass + dist loss: y = t>>2 fixed, 32 i(z)'s.
  {
    // od prefetch issued here (not earlier): consumed only after the j-loop,
    // so the loads hide under ~2k cycles of envelope math without pinning
    // 32 VGPRs through the Y pass.
    int yl = t >> 2, izb = (t & 3) * 32;
    size_t odb = (size_t)(2 * b + 1) * M_SPATIAL + (size_t)xx * 16384 +
                 (size_t)yl * 128 + (size_t)izb;
    const float4* o4 = (const float4*)(od + odb);
    float4 ovv[8];
#pragma unroll
    for (int r = 0; r < 8; ++r) ovv[r] = o4[r];

    float best[32];
    f32x2 mc2[32];
#pragma unroll
    for (int k = 0; k < 32; ++k) {
      best[k] = 3.0e38f;
      float m = -2.0f * (float)(izb + k);
      mc2[k] = (f32x2){m, m};
    }
    f32x2 jv = {0.0f, 1.0f};
#pragma unroll 4
    for (int j = 0; j < 128; j += 2) {
      f32x2 hv = {sbuf[j * 129 + yl], sbuf[(j + 1) * 129 + yl]};
#pragma unroll
      for (int k = 0; k < 32; ++k) {
        f32x2 v = pk_fma(mc2[k], jv, hv);
        best[k] = min3f(v.x, v.y, best[k]);
      }
      jv += (f32x2){2.0f, 2.0f};
    }
    const float* of = (const float*)ovv;
    float dist = 0.f;
#pragma unroll
    for (int k = 0; k < 32; ++k) {
      int i = izb + k;
      float dv = (float)(i * i) + best[k];   // exact squared EDT
      if (dv > 0.f) dist += fabsf(of[k] - sqrtf(dv));
    }
    float r = wave_redf(dist);
    int lane = t & 63, w = t >> 6;
    if (lane == 0) sred[w] = r;
  }
  __syncthreads();
  if (t == 0) {
    float s = 0.f;
#pragma unroll
    for (int q = 0; q < 8; ++q) s += sred[q];
    part[4096 + blk] = (double)s;
  }
}

// ---------------------------------------------------------------------------
// k_final: reduce partials (1024 ce/dice slots, 256 dist slots) -> loss.
// ---------------------------------------------------------------------------
__global__ __launch_bounds__(256) void k_final(const double* __restrict__ part,
                                               const float* __restrict__ wptr,
                                               float* __restrict__ out) {
  int i = threadIdx.x;
  double ce  = part[i] + part[i + 256] + part[i + 512] + part[i + 768];
  double p0  = part[1024 + i] + part[1024 + i + 256];
  double p1  = part[1536 + i] + part[1536 + i + 256];
  double pt0 = part[2048 + i] + part[2048 + i + 256];
  double pt1 = part[2560 + i] + part[2560 + i + 256];
  double t0  = part[3072 + i] + part[3072 + i + 256];
  double t1  = part[3584 + i] + part[3584 + i + 256];
  double ds  = part[4096 + i];   // 256 kCD blocks, one slot per thread

  ce = wave_redd(ce); p0 = wave_redd(p0); p1 = wave_redd(p1);
  pt0 = wave_redd(pt0); pt1 = wave_redd(pt1);
  t0 = wave_redd(t0); t1 = wave_redd(t1); ds = wave_redd(ds);

  __shared__ double sm[4][8];
  int lane = threadIdx.x & 63, w = threadIdx.x >> 6;
  if (lane == 0) {
    sm[w][0] = ce; sm[w][1] = p0; sm[w][2] = p1; sm[w][3] = pt0;
    sm[w][4] = pt1; sm[w][5] = t0; sm[w][6] = t1; sm[w][7] = ds;
  }
  __syncthreads();
  if (threadIdx.x == 0) {
    double a[8];
    for (int q = 0; q < 8; ++q) a[q] = sm[0][q] + sm[1][q] + sm[2][q] + sm[3][q];
    double cem = a[0] / 4194304.0;
    double dice0 = (2.0 * a[3] + 1.0) / (a[1] + a[5] + 1.0);
    double dice1 = (2.0 * a[4] + 1.0) / (a[2] + a[6] + 1.0);
    double ldice = 1.0 - 0.5 * (dice0 + dice1);
    double msum = a[5] + a[6];
    double ldist = (msum == 0.0) ? 0.0 : a[7] / fmax(msum, 1e-12);
    out[0] = (float)(cem + ldice + (double)wptr[0] * ldist);
  }
}

extern "C" void kernel_launch(void* const* d_in, const int* in_sizes, int n_in,
                              void* d_out, int out_size, void* d_ws, size_t ws_size,
                              hipStream_t stream) {
  const float* outputs      = (const float*)d_in[0];
  const float* outputs_dist = (const float*)d_in[1];
  const int*   y            = (const int*)d_in[2];
  const float* wptr         = (const float*)d_in[3];
  float* out = (float*)d_out;

  double* part = (double*)d_ws;                    // 4352 doubles
  float* g = (float*)((char*)d_ws + 65536);        // 16 MiB h field

  kAB<<<1024, 256, 0, stream>>>(y, outputs, g, part);      // X scan + CE/dice
  kCD<<<256, 512, 0, stream>>>(g, outputs_dist, part);     // Y+Z EDT + dist
  k_final<<<1, 256, 0, stream>>>(part, wptr, out);
}

// Round 7
// 160.703 us; speedup vs baseline: 1.0378x; 1.0282x over previous
//
#include <hip/hip_runtime.h>
#include <math.h>

#define M_SPATIAL 2097152  // 128^3

__device__ __forceinline__ float wave_redf(float v) {
#pragma unroll
  for (int o = 32; o > 0; o >>= 1) v += __shfl_down(v, o, 64);
  return v;
}
__device__ __forceinline__ double wave_redd(double v) {
#pragma unroll
  for (int o = 32; o > 0; o >>= 1) v += __shfl_down(v, o, 64);
  return v;
}
// Forced 3-input min (VOP3 v_min3_f32); exact, order-independent.
__device__ __forceinline__ float min3f(float a, float b, float c) {
  float d;
  asm("v_min3_f32 %0, %1, %2, %3" : "=v"(d) : "v"(a), "v"(b), "v"(c));
  return d;
}

// part layout (doubles):
// [0..1023]=ce  [1024..2047]=p  [2048..3071]=pt  [3072..4095]=t
// [4096..5119]=dist (1024 kD blocks)

// ---------------------------------------------------------------------------
// kAB: X-axis EDT (blocked parallel scan) FUSED with CE + dice partials.
// xc is already batch-offset -> spatial-only index sp (round-2 OOB lesson).
// Writes h = gX + y^2 for the Y pass.
// ---------------------------------------------------------------------------
__global__ __launch_bounds__(256) void kAB(const int* __restrict__ y,
                                           const float* __restrict__ outputs,
                                           float* __restrict__ g,
                                           double* __restrict__ part) {
  int blk = blockIdx.x;            // b*512 + yy*4 + zq
  int b  = blk >> 9;
  int yy = (blk >> 2) & 127;
  int zq = blk & 3;
  int t  = threadIdx.x;
  int c  = t >> 5;                 // x-chunk 0..7 (16 x each)
  int zl = t & 31;                 // z within 32-chunk
  int x0 = c * 16;
  size_t sp   = (size_t)yy * 128 + (size_t)zq * 32 + zl;    // spatial-only
  size_t base = (size_t)b * M_SPATIAL + sp;                 // batch + spatial
  const float* xc = outputs + (size_t)(b * 2 + 1) * M_SPATIAL;

  int yb[16];
  float xv[16];
#pragma unroll
  for (int k = 0; k < 16; ++k) yb[k] = y[base + (size_t)(x0 + k) * 16384];
#pragma unroll
  for (int k = 0; k < 16; ++k) xv[k] = xc[sp + (size_t)(x0 + k) * 16384];

  int lastE = -200, nextE = 400;
#pragma unroll
  for (int k = 0; k < 16; ++k) lastE = (yb[k] == 1) ? lastE : (x0 + k);
#pragma unroll
  for (int k = 15; k >= 0; --k) nextE = (yb[k] == 1) ? nextE : (x0 + k);

  __shared__ int lE[8][32];
  __shared__ int nE[8][32];
  lE[c][zl] = lastE;
  nE[c][zl] = nextE;
  __syncthreads();

  int carryL = -200, carryN = 400;
#pragma unroll
  for (int q = 0; q < 7; ++q) {
    if (q < c)     carryL = max(carryL, lE[q][zl]);
    if (q + 1 > c) carryN = min(carryN, nE[q + 1][zl]);
  }

  float yy2f = (float)(yy * yy);
  float hinf = 1000000.f + yy2f;

  int df[16];
  int ll = carryL;
#pragma unroll
  for (int k = 0; k < 16; ++k) {
    ll = (yb[k] == 1) ? ll : (x0 + k);
    df[k] = min(x0 + k - ll, 200);
  }
  float ov[16];
  int nn = carryN;
#pragma unroll
  for (int k = 15; k >= 0; --k) {
    nn = (yb[k] == 1) ? nn : (x0 + k);
    int m = min(df[k], min(nn - (x0 + k), 200));
    ov[k] = (m >= 128) ? hinf : ((float)(m * m) + yy2f);
  }
#pragma unroll
  for (int k = 0; k < 16; ++k) g[base + (size_t)(x0 + k) * 16384] = ov[k];

  float ce = 0.f, ps = 0.f, pts = 0.f, tsum = 0.f;
#pragma unroll
  for (int k = 0; k < 16; ++k) {
    float tt = (yb[k] == 1) ? 1.0f : 0.0f;
    float xx = xv[k];
    ce += fmaxf(xx, 0.0f) - xx * tt + log1pf(expf(-fabsf(xx)));
    float p = 1.0f / (1.0f + expf(-xx));
    ps += p; pts += p * tt; tsum += tt;
  }
  float r0 = wave_redf(ce), r1 = wave_redf(ps), r2 = wave_redf(pts), r3 = wave_redf(tsum);
  __shared__ float sm[4][4];
  int lane = t & 63, w = t >> 6;
  if (lane == 0) { sm[w][0] = r0; sm[w][1] = r1; sm[w][2] = r2; sm[w][3] = r3; }
  __syncthreads();
  if (t == 0) {
    part[blk]        = (double)(sm[0][0] + sm[1][0] + sm[2][0] + sm[3][0]);
    part[1024 + blk] = (double)(sm[0][1] + sm[1][1] + sm[2][1] + sm[3][1]);
    part[2048 + blk] = (double)(sm[0][2] + sm[1][2] + sm[2][2] + sm[3][2]);
    part[3072 + blk] = (double)(sm[0][3] + sm[1][3] + sm[2][3] + sm[3][3]);
  }
}

// ---------------------------------------------------------------------------
// kC: Y-axis pass, UNFUSED (round-6 lesson: the fused 1-block/CU kCD has a
// ~21 us lockstep-stall floor; 1024 independent blocks -> 4 blocks/CU, waves
// of different blocks overlap each other's LDS/barrier stalls).
// Inner loop at the 6-cyc floor: fma, fma, forced v_min3_f32 per (2j, i).
// In-place on g. Writes h' = dY + z^2 for the Z pass.
// ---------------------------------------------------------------------------
__global__ __launch_bounds__(256) void kC_edty(float* __restrict__ g) {
  __shared__ float hl[128 * 33];   // hl[j*33 + zl]
  int blk = blockIdx.x;            // b*512 + xx*4 + zc
  int b = blk >> 9, xx = (blk >> 2) & 127, zc = blk & 3;
  int t = threadIdx.x;
  size_t rb = (size_t)b * M_SPATIAL + (size_t)xx * 16384 + (size_t)zc * 32;

#pragma unroll
  for (int r = 0; r < 4; ++r) {
    int i4 = t + r * 256;          // 0..1023 float4 units
    int j = i4 >> 3, w = i4 & 7;   // row j, 4*w z-offset
    float4 v = *(const float4*)(g + rb + (size_t)j * 128 + 4 * w);
    hl[j * 33 + 4 * w + 0] = v.x;
    hl[j * 33 + 4 * w + 1] = v.y;
    hl[j * 33 + 4 * w + 2] = v.z;
    hl[j * 33 + 4 * w + 3] = v.w;
  }
  __syncthreads();

  int zl = t & 31, ig = t >> 5;
  float best[16], mc[16];
#pragma unroll
  for (int k = 0; k < 16; ++k) {
    best[k] = 3.0e38f;
    mc[k] = -2.0f * (float)(ig * 16 + k);
  }
#pragma unroll 2
  for (int j = 0; j < 128; j += 2) {
    float h0 = hl[j * 33 + zl];
    float h1 = hl[(j + 1) * 33 + zl];
    float j0 = (float)j, j1 = (float)(j + 1);
#pragma unroll
    for (int k = 0; k < 16; ++k) {
      float v0 = fmaf(mc[k], j0, h0);
      float v1 = fmaf(mc[k], j1, h1);
      best[k] = min3f(v0, v1, best[k]);
    }
  }
  int gz = zc * 32 + zl;
  float zq = (float)(gz * gz);
  size_t ob = rb + zl;
#pragma unroll
  for (int k = 0; k < 16; ++k) {
    int i = ig * 16 + k;
    float dY = (float)(i * i) + best[k];   // exact int
    g[ob + (size_t)i * 128] = dY + zq;     // h for Z pass
  }
}

// ---------------------------------------------------------------------------
// kD: Z-axis pass (contiguous lines) + fused dist-loss partial.
// Same min3 inner loop; round-1-verified layouts.
// ---------------------------------------------------------------------------
__global__ __launch_bounds__(256) void kD_edtz_dist(const float* __restrict__ g,
                                                    const float* __restrict__ od,
                                                    double* __restrict__ part) {
  __shared__ float hl[128 * 33];   // hl[z*33 + yl]
  __shared__ float sred[4];
  int blk = blockIdx.x;            // b*512 + xx*4 + yc
  int b = blk >> 9, xx = (blk >> 2) & 127, yc = blk & 3;
  int t = threadIdx.x;
  size_t rb = (size_t)b * M_SPATIAL + (size_t)xx * 16384 + (size_t)yc * 4096;
  int yl = t & 31, ig = t >> 5;

  // Prefetch od (this thread's 16 consecutive z) early to hide latency.
  size_t odb = (size_t)(2 * b + 1) * M_SPATIAL + (size_t)xx * 16384 +
               (size_t)yc * 4096 + (size_t)yl * 128 + (size_t)ig * 16;
  const float4* o4 = (const float4*)(od + odb);
  float4 ov[4];
#pragma unroll
  for (int r = 0; r < 4; ++r) ov[r] = o4[r];

  const float4* h4 = (const float4*)(g + rb);
#pragma unroll
  for (int r = 0; r < 4; ++r) {
    int i4 = t + r * 256;
    float4 v = h4[i4];
    int flat = i4 * 4;
    int z = flat & 127, yw = flat >> 7;  // z%4==0, all 4 comps same yw
    hl[(z + 0) * 33 + yw] = v.x;
    hl[(z + 1) * 33 + yw] = v.y;
    hl[(z + 2) * 33 + yw] = v.z;
    hl[(z + 3) * 33 + yw] = v.w;
  }
  __syncthreads();

  float best[16], mc[16];
#pragma unroll
  for (int k = 0; k < 16; ++k) {
    best[k] = 3.0e38f;
    mc[k] = -2.0f * (float)(ig * 16 + k);
  }
#pragma unroll 2
  for (int j = 0; j < 128; j += 2) {
    float h0 = hl[j * 33 + yl];
    float h1 = hl[(j + 1) * 33 + yl];
    float j0 = (float)j, j1 = (float)(j + 1);
#pragma unroll
    for (int k = 0; k < 16; ++k) {
      float v0 = fmaf(mc[k], j0, h0);
      float v1 = fmaf(mc[k], j1, h1);
      best[k] = min3f(v0, v1, best[k]);
    }
  }
  const float* of = (const float*)ov;
  float dist = 0.f;
#pragma unroll
  for (int k = 0; k < 16; ++k) {
    int i = ig * 16 + k;
    float dv = (float)(i * i) + best[k];   // exact squared EDT
    if (dv > 0.f) dist += fabsf(of[k] - sqrtf(dv));
  }
  float r = wave_redf(dist);
  int lane = t & 63, w = t >> 6;
  if (lane == 0) sred[w] = r;
  __syncthreads();
  if (t == 0) part[4096 + blk] = (double)(sred[0] + sred[1] + sred[2] + sred[3]);
}

// ---------------------------------------------------------------------------
// k_final: reduce partials (4x1024 ce/dice slots, 1024 dist slots) -> loss.
// ---------------------------------------------------------------------------
__global__ __launch_bounds__(256) void k_final(const double* __restrict__ part,
                                               const float* __restrict__ wptr,
                                               float* __restrict__ out) {
  int i = threadIdx.x;
  double ce  = part[i] + part[i + 256] + part[i + 512] + part[i + 768];
  double p0  = part[1024 + i] + part[1024 + i + 256];
  double p1  = part[1536 + i] + part[1536 + i + 256];
  double pt0 = part[2048 + i] + part[2048 + i + 256];
  double pt1 = part[2560 + i] + part[2560 + i + 256];
  double t0  = part[3072 + i] + part[3072 + i + 256];
  double t1  = part[3584 + i] + part[3584 + i + 256];
  double ds  = part[4096 + i] + part[4096 + i + 256] + part[4096 + i + 512] + part[4096 + i + 768];

  ce = wave_redd(ce); p0 = wave_redd(p0); p1 = wave_redd(p1);
  pt0 = wave_redd(pt0); pt1 = wave_redd(pt1);
  t0 = wave_redd(t0); t1 = wave_redd(t1); ds = wave_redd(ds);

  __shared__ double sm[4][8];
  int lane = threadIdx.x & 63, w = threadIdx.x >> 6;
  if (lane == 0) {
    sm[w][0] = ce; sm[w][1] = p0; sm[w][2] = p1; sm[w][3] = pt0;
    sm[w][4] = pt1; sm[w][5] = t0; sm[w][6] = t1; sm[w][7] = ds;
  }
  __syncthreads();
  if (threadIdx.x == 0) {
    double a[8];
    for (int q = 0; q < 8; ++q) a[q] = sm[0][q] + sm[1][q] + sm[2][q] + sm[3][q];
    double cem = a[0] / 4194304.0;
    double dice0 = (2.0 * a[3] + 1.0) / (a[1] + a[5] + 1.0);
    double dice1 = (2.0 * a[4] + 1.0) / (a[2] + a[6] + 1.0);
    double ldice = 1.0 - 0.5 * (dice0 + dice1);
    double msum = a[5] + a[6];
    double ldist = (msum == 0.0) ? 0.0 : a[7] / fmax(msum, 1e-12);
    out[0] = (float)(cem + ldice + (double)wptr[0] * ldist);
  }
}

extern "C" void kernel_launch(void* const* d_in, const int* in_sizes, int n_in,
                              void* d_out, int out_size, void* d_ws, size_t ws_size,
                              hipStream_t stream) {
  const float* outputs      = (const float*)d_in[0];
  const float* outputs_dist = (const float*)d_in[1];
  const int*   y            = (const int*)d_in[2];
  const float* wptr         = (const float*)d_in[3];
  float* out = (float*)d_out;

  double* part = (double*)d_ws;                    // 5120 doubles
  float* g = (float*)((char*)d_ws + 65536);        // 16 MiB h field

  kAB<<<1024, 256, 0, stream>>>(y, outputs, g, part);            // X + CE/dice
  kC_edty<<<1024, 256, 0, stream>>>(g);                          // Y pass
  kD_edtz_dist<<<1024, 256, 0, stream>>>(g, outputs_dist, part); // Z + dist
  k_final<<<1, 256, 0, stream>>>(part, wptr, out);
}

// Round 8
// 141.931 us; speedup vs baseline: 1.1751x; 1.1323x over previous
//
#include <hip/hip_runtime.h>
#include <math.h>

#define M_SPATIAL 2097152  // 128^3

__device__ __forceinline__ float wave_redf(float v) {
#pragma unroll
  for (int o = 32; o > 0; o >>= 1) v += __shfl_down(v, o, 64);
  return v;
}
__device__ __forceinline__ double wave_redd(double v) {
#pragma unroll
  for (int o = 32; o > 0; o >>= 1) v += __shfl_down(v, o, 64);
  return v;
}
// Forced 3-input min (VOP3 v_min3_f32); exact, order-independent.
__device__ __forceinline__ float min3f(float a, float b, float c) {
  float d;
  asm("v_min3_f32 %0, %1, %2, %3" : "=v"(d) : "v"(a), "v"(b), "v"(c));
  return d;
}

// part layout (doubles):
// [0..1023]=ce  [1024..2047]=p  [2048..3071]=pt  [3072..4095]=t
// [4096..5119]=dist (1024 kD blocks)

// ---------------------------------------------------------------------------
// kAB: X-axis EDT (blocked parallel scan) FUSED with CE + dice partials.
// xc is already batch-offset -> spatial-only index sp (round-2 OOB lesson).
// Writes h = gX + y^2 for the Y pass.
// ---------------------------------------------------------------------------
__global__ __launch_bounds__(256) void kAB(const int* __restrict__ y,
                                           const float* __restrict__ outputs,
                                           float* __restrict__ g,
                                           double* __restrict__ part) {
  int blk = blockIdx.x;            // b*512 + yy*4 + zq
  int b  = blk >> 9;
  int yy = (blk >> 2) & 127;
  int zq = blk & 3;
  int t  = threadIdx.x;
  int c  = t >> 5;                 // x-chunk 0..7 (16 x each)
  int zl = t & 31;                 // z within 32-chunk
  int x0 = c * 16;
  size_t sp   = (size_t)yy * 128 + (size_t)zq * 32 + zl;    // spatial-only
  size_t base = (size_t)b * M_SPATIAL + sp;                 // batch + spatial
  const float* xc = outputs + (size_t)(b * 2 + 1) * M_SPATIAL;

  int yb[16];
  float xv[16];
#pragma unroll
  for (int k = 0; k < 16; ++k) yb[k] = y[base + (size_t)(x0 + k) * 16384];
#pragma unroll
  for (int k = 0; k < 16; ++k) xv[k] = xc[sp + (size_t)(x0 + k) * 16384];

  int lastE = -200, nextE = 400;
#pragma unroll
  for (int k = 0; k < 16; ++k) lastE = (yb[k] == 1) ? lastE : (x0 + k);
#pragma unroll
  for (int k = 15; k >= 0; --k) nextE = (yb[k] == 1) ? nextE : (x0 + k);

  __shared__ int lE[8][32];
  __shared__ int nE[8][32];
  lE[c][zl] = lastE;
  nE[c][zl] = nextE;
  __syncthreads();

  int carryL = -200, carryN = 400;
#pragma unroll
  for (int q = 0; q < 7; ++q) {
    if (q < c)     carryL = max(carryL, lE[q][zl]);
    if (q + 1 > c) carryN = min(carryN, nE[q + 1][zl]);
  }

  float yy2f = (float)(yy * yy);
  float hinf = 1000000.f + yy2f;

  int df[16];
  int ll = carryL;
#pragma unroll
  for (int k = 0; k < 16; ++k) {
    ll = (yb[k] == 1) ? ll : (x0 + k);
    df[k] = min(x0 + k - ll, 200);
  }
  float ov[16];
  int nn = carryN;
#pragma unroll
  for (int k = 15; k >= 0; --k) {
    nn = (yb[k] == 1) ? nn : (x0 + k);
    int m = min(df[k], min(nn - (x0 + k), 200));
    ov[k] = (m >= 128) ? hinf : ((float)(m * m) + yy2f);
  }
#pragma unroll
  for (int k = 0; k < 16; ++k) g[base + (size_t)(x0 + k) * 16384] = ov[k];

  float ce = 0.f, ps = 0.f, pts = 0.f, tsum = 0.f;
#pragma unroll
  for (int k = 0; k < 16; ++k) {
    float tt = (yb[k] == 1) ? 1.0f : 0.0f;
    float xx = xv[k];
    ce += fmaxf(xx, 0.0f) - xx * tt + log1pf(expf(-fabsf(xx)));
    float p = 1.0f / (1.0f + expf(-xx));
    ps += p; pts += p * tt; tsum += tt;
  }
  float r0 = wave_redf(ce), r1 = wave_redf(ps), r2 = wave_redf(pts), r3 = wave_redf(tsum);
  __shared__ float sm[4][4];
  int lane = t & 63, w = t >> 6;
  if (lane == 0) { sm[w][0] = r0; sm[w][1] = r1; sm[w][2] = r2; sm[w][3] = r3; }
  __syncthreads();
  if (t == 0) {
    part[blk]        = (double)(sm[0][0] + sm[1][0] + sm[2][0] + sm[3][0]);
    part[1024 + blk] = (double)(sm[0][1] + sm[1][1] + sm[2][1] + sm[3][1]);
    part[2048 + blk] = (double)(sm[0][2] + sm[1][2] + sm[2][2] + sm[3][2]);
    part[3072 + blk] = (double)(sm[0][3] + sm[1][3] + sm[2][3] + sm[3][3]);
  }
}

// ---------------------------------------------------------------------------
// kC: Y-axis pass with EXACT windowed envelope.
// For output i, parabolas outside [ibase-8, ibase+23] contribute
// >= min((k+9)^2, (24-k)^2); if the windowed min is <= that bound, it IS the
// global min (payload >= 0). Window check fails -> wave falls back to the
// full 128-j loop (bit-identical to round-7 code; fires only for inputs with
// EDT distance > ~8, impossible for Bernoulli(1/2) masks).
// LDS rows padded +-8 with 1e9 so the window loop is branch-free.
// ---------------------------------------------------------------------------
__global__ __launch_bounds__(256) void kC_edty(float* __restrict__ g) {
  __shared__ float hl[144 * 33];   // rows = j+8, j in [-8, 136)
  int blk = blockIdx.x;            // b*512 + xx*4 + zc
  int b = blk >> 9, xx = (blk >> 2) & 127, zc = blk & 3;
  int t = threadIdx.x;
  size_t rb = (size_t)b * M_SPATIAL + (size_t)xx * 16384 + (size_t)zc * 32;

  // Pad rows 0..7 and 136..143 with a value that can never win.
#pragma unroll
  for (int idx = t; idx < 264; idx += 256) {      // 8*33 = 264
    hl[idx] = 1.0e9f;
    hl[136 * 33 + idx] = 1.0e9f;
  }
#pragma unroll
  for (int r = 0; r < 4; ++r) {
    int i4 = t + r * 256;          // 0..1023 float4 units
    int j = i4 >> 3, w = i4 & 7;   // row j, 4*w z-offset
    float4 v = *(const float4*)(g + rb + (size_t)j * 128 + 4 * w);
    hl[(j + 8) * 33 + 4 * w + 0] = v.x;
    hl[(j + 8) * 33 + 4 * w + 1] = v.y;
    hl[(j + 8) * 33 + 4 * w + 2] = v.z;
    hl[(j + 8) * 33 + 4 * w + 3] = v.w;
  }
  __syncthreads();

  int zl = t & 31, ig = t >> 5;
  int ibase = ig * 16;
  float best[16], mc[16];
#pragma unroll
  for (int k = 0; k < 16; ++k) {
    best[k] = 3.0e38f;
    mc[k] = -2.0f * (float)(ibase + k);
  }
  // Windowed pass: j = ibase-8 + 2p (+1), LDS row = j+8 = ibase+2p.
  float jb = (float)(ibase - 8);
#pragma unroll 4
  for (int p = 0; p < 16; ++p) {
    float h0 = hl[(ibase + 2 * p) * 33 + zl];
    float h1 = hl[(ibase + 2 * p + 1) * 33 + zl];
    float j0 = jb + (float)(2 * p), j1 = jb + (float)(2 * p + 1);
#pragma unroll
    for (int k = 0; k < 16; ++k) {
      float v0 = fmaf(mc[k], j0, h0);
      float v1 = fmaf(mc[k], j1, h1);
      best[k] = min3f(v0, v1, best[k]);
    }
  }
  float dv[16];
  int ok = 1;
#pragma unroll
  for (int k = 0; k < 16; ++k) {
    int i = ibase + k;
    dv[k] = (float)(i * i) + best[k];           // exact windowed dY^2
    float bnd = (float)min((k + 9) * (k + 9), (24 - k) * (24 - k));
    ok &= (dv[k] <= bnd);
  }
  if (!__all(ok)) {                              // exactness not certified
#pragma unroll
    for (int k = 0; k < 16; ++k) best[k] = 3.0e38f;
#pragma unroll 2
    for (int j = 0; j < 128; j += 2) {
      float h0 = hl[(j + 8) * 33 + zl];
      float h1 = hl[(j + 9) * 33 + zl];
      float j0 = (float)j, j1 = (float)(j + 1);
#pragma unroll
      for (int k = 0; k < 16; ++k) {
        float v0 = fmaf(mc[k], j0, h0);
        float v1 = fmaf(mc[k], j1, h1);
        best[k] = min3f(v0, v1, best[k]);
      }
    }
#pragma unroll
    for (int k = 0; k < 16; ++k) {
      int i = ibase + k;
      dv[k] = (float)(i * i) + best[k];
    }
  }
  int gz = zc * 32 + zl;
  float zq = (float)(gz * gz);
  size_t ob = rb + zl;
#pragma unroll
  for (int k = 0; k < 16; ++k) {
    int i = ibase + k;
    g[ob + (size_t)i * 128] = dv[k] + zq;        // h for Z pass
  }
}

// ---------------------------------------------------------------------------
// kD: Z-axis pass + fused dist-loss partial. Same windowed-exact envelope.
// ---------------------------------------------------------------------------
__global__ __launch_bounds__(256) void kD_edtz_dist(const float* __restrict__ g,
                                                    const float* __restrict__ od,
                                                    double* __restrict__ part) {
  __shared__ float hl[144 * 33];   // rows = z+8
  __shared__ float sred[4];
  int blk = blockIdx.x;            // b*512 + xx*4 + yc
  int b = blk >> 9, xx = (blk >> 2) & 127, yc = blk & 3;
  int t = threadIdx.x;
  size_t rb = (size_t)b * M_SPATIAL + (size_t)xx * 16384 + (size_t)yc * 4096;
  int yl = t & 31, ig = t >> 5;
  int ibase = ig * 16;

  // Prefetch od (this thread's 16 consecutive z) early to hide latency.
  size_t odb = (size_t)(2 * b + 1) * M_SPATIAL + (size_t)xx * 16384 +
               (size_t)yc * 4096 + (size_t)yl * 128 + (size_t)ibase;
  const float4* o4 = (const float4*)(od + odb);
  float4 ov[4];
#pragma unroll
  for (int r = 0; r < 4; ++r) ov[r] = o4[r];

#pragma unroll
  for (int idx = t; idx < 264; idx += 256) {
    hl[idx] = 1.0e9f;
    hl[136 * 33 + idx] = 1.0e9f;
  }
  const float4* h4 = (const float4*)(g + rb);
#pragma unroll
  for (int r = 0; r < 4; ++r) {
    int i4 = t + r * 256;
    float4 v = h4[i4];
    int flat = i4 * 4;
    int z = flat & 127, yw = flat >> 7;  // z%4==0, all 4 comps same yw
    hl[(z + 8) * 33 + yw] = v.x;
    hl[(z + 9) * 33 + yw] = v.y;
    hl[(z + 10) * 33 + yw] = v.z;
    hl[(z + 11) * 33 + yw] = v.w;
  }
  __syncthreads();

  float best[16], mc[16];
#pragma unroll
  for (int k = 0; k < 16; ++k) {
    best[k] = 3.0e38f;
    mc[k] = -2.0f * (float)(ibase + k);
  }
  float jb = (float)(ibase - 8);
#pragma unroll 4
  for (int p = 0; p < 16; ++p) {
    float h0 = hl[(ibase + 2 * p) * 33 + yl];
    float h1 = hl[(ibase + 2 * p + 1) * 33 + yl];
    float j0 = jb + (float)(2 * p), j1 = jb + (float)(2 * p + 1);
#pragma unroll
    for (int k = 0; k < 16; ++k) {
      float v0 = fmaf(mc[k], j0, h0);
      float v1 = fmaf(mc[k], j1, h1);
      best[k] = min3f(v0, v1, best[k]);
    }
  }
  float dv[16];
  int ok = 1;
#pragma unroll
  for (int k = 0; k < 16; ++k) {
    int i = ibase + k;
    dv[k] = (float)(i * i) + best[k];
    float bnd = (float)min((k + 9) * (k + 9), (24 - k) * (24 - k));
    ok &= (dv[k] <= bnd);
  }
  if (!__all(ok)) {
#pragma unroll
    for (int k = 0; k < 16; ++k) best[k] = 3.0e38f;
#pragma unroll 2
    for (int j = 0; j < 128; j += 2) {
      float h0 = hl[(j + 8) * 33 + yl];
      float h1 = hl[(j + 9) * 33 + yl];
      float j0 = (float)j, j1 = (float)(j + 1);
#pragma unroll
      for (int k = 0; k < 16; ++k) {
        float v0 = fmaf(mc[k], j0, h0);
        float v1 = fmaf(mc[k], j1, h1);
        best[k] = min3f(v0, v1, best[k]);
      }
    }
#pragma unroll
    for (int k = 0; k < 16; ++k) {
      int i = ibase + k;
      dv[k] = (float)(i * i) + best[k];
    }
  }
  const float* of = (const float*)ov;
  float dist = 0.f;
#pragma unroll
  for (int k = 0; k < 16; ++k) {
    if (dv[k] > 0.f) dist += fabsf(of[k] - sqrtf(dv[k]));
  }
  float r = wave_redf(dist);
  int lane = t & 63, w = t >> 6;
  if (lane == 0) sred[w] = r;
  __syncthreads();
  if (t == 0) part[4096 + blk] = (double)(sred[0] + sred[1] + sred[2] + sred[3]);
}

// ---------------------------------------------------------------------------
// k_final: reduce partials (4x1024 ce/dice slots, 1024 dist slots) -> loss.
// ---------------------------------------------------------------------------
__global__ __launch_bounds__(256) void k_final(const double* __restrict__ part,
                                               const float* __restrict__ wptr,
                                               float* __restrict__ out) {
  int i = threadIdx.x;
  double ce  = part[i] + part[i + 256] + part[i + 512] + part[i + 768];
  double p0  = part[1024 + i] + part[1024 + i + 256];
  double p1  = part[1536 + i] + part[1536 + i + 256];
  double pt0 = part[2048 + i] + part[2048 + i + 256];
  double pt1 = part[2560 + i] + part[2560 + i + 256];
  double t0  = part[3072 + i] + part[3072 + i + 256];
  double t1  = part[3584 + i] + part[3584 + i + 256];
  double ds  = part[4096 + i] + part[4096 + i + 256] + part[4096 + i + 512] + part[4096 + i + 768];

  ce = wave_redd(ce); p0 = wave_redd(p0); p1 = wave_redd(p1);
  pt0 = wave_redd(pt0); pt1 = wave_redd(pt1);
  t0 = wave_redd(t0); t1 = wave_redd(t1); ds = wave_redd(ds);

  __shared__ double sm[4][8];
  int lane = threadIdx.x & 63, w = threadIdx.x >> 6;
  if (lane == 0) {
    sm[w][0] = ce; sm[w][1] = p0; sm[w][2] = p1; sm[w][3] = pt0;
    sm[w][4] = pt1; sm[w][5] = t0; sm[w][6] = t1; sm[w][7] = ds;
  }
  __syncthreads();
  if (threadIdx.x == 0) {
    double a[8];
    for (int q = 0; q < 8; ++q) a[q] = sm[0][q] + sm[1][q] + sm[2][q] + sm[3][q];
    double cem = a[0] / 4194304.0;
    double dice0 = (2.0 * a[3] + 1.0) / (a[1] + a[5] + 1.0);
    double dice1 = (2.0 * a[4] + 1.0) / (a[2] + a[6] + 1.0);
    double ldice = 1.0 - 0.5 * (dice0 + dice1);
    double msum = a[5] + a[6];
    double ldist = (msum == 0.0) ? 0.0 : a[7] / fmax(msum, 1e-12);
    out[0] = (float)(cem + ldice + (double)wptr[0] * ldist);
  }
}

extern "C" void kernel_launch(void* const* d_in, const int* in_sizes, int n_in,
                              void* d_out, int out_size, void* d_ws, size_t ws_size,
                              hipStream_t stream) {
  const float* outputs      = (const float*)d_in[0];
  const float* outputs_dist = (const float*)d_in[1];
  const int*   y            = (const int*)d_in[2];
  const float* wptr         = (const float*)d_in[3];
  float* out = (float*)d_out;

  double* part = (double*)d_ws;                    // 5120 doubles
  float* g = (float*)((char*)d_ws + 65536);        // 16 MiB h field

  kAB<<<1024, 256, 0, stream>>>(y, outputs, g, part);            // X + CE/dice
  kC_edty<<<1024, 256, 0, stream>>>(g);                          // Y pass
  kD_edtz_dist<<<1024, 256, 0, stream>>>(g, outputs_dist, part); // Z + dist
  k_final<<<1, 256, 0, stream>>>(part, wptr, out);
}

// Round 9
// 139.560 us; speedup vs baseline: 1.1951x; 1.0170x over previous
//
#include <hip/hip_runtime.h>
#include <math.h>

#define M_SPATIAL 2097152  // 128^3

__device__ __forceinline__ float wave_redf(float v) {
#pragma unroll
  for (int o = 32; o > 0; o >>= 1) v += __shfl_down(v, o, 64);
  return v;
}
__device__ __forceinline__ double wave_redd(double v) {
#pragma unroll
  for (int o = 32; o > 0; o >>= 1) v += __shfl_down(v, o, 64);
  return v;
}
// Forced 3-input min (VOP3 v_min3_f32); exact, order-independent.
__device__ __forceinline__ float min3f(float a, float b, float c) {
  float d;
  asm("v_min3_f32 %0, %1, %2, %3" : "=v"(d) : "v"(a), "v"(b), "v"(c));
  return d;
}

// part layout (doubles):
// [0..1023]=ce  [1024..2047]=p  [2048..3071]=pt  [3072..4095]=t
// [4096..4351]=dist (256 kCD blocks)

// ---------------------------------------------------------------------------
// kAB: X-axis EDT (blocked parallel scan) FUSED with CE + dice partials.
// xc is already batch-offset -> spatial-only index sp (round-2 OOB lesson).
// Writes h = gX + y^2 for the Y pass. (Unchanged from round 8 — proven.)
// ---------------------------------------------------------------------------
__global__ __launch_bounds__(256) void kAB(const int* __restrict__ y,
                                           const float* __restrict__ outputs,
                                           float* __restrict__ g,
                                           double* __restrict__ part) {
  int blk = blockIdx.x;            // b*512 + yy*4 + zq
  int b  = blk >> 9;
  int yy = (blk >> 2) & 127;
  int zq = blk & 3;
  int t  = threadIdx.x;
  int c  = t >> 5;                 // x-chunk 0..7 (16 x each)
  int zl = t & 31;                 // z within 32-chunk
  int x0 = c * 16;
  size_t sp   = (size_t)yy * 128 + (size_t)zq * 32 + zl;    // spatial-only
  size_t base = (size_t)b * M_SPATIAL + sp;                 // batch + spatial
  const float* xc = outputs + (size_t)(b * 2 + 1) * M_SPATIAL;

  int yb[16];
  float xv[16];
#pragma unroll
  for (int k = 0; k < 16; ++k) yb[k] = y[base + (size_t)(x0 + k) * 16384];
#pragma unroll
  for (int k = 0; k < 16; ++k) xv[k] = xc[sp + (size_t)(x0 + k) * 16384];

  int lastE = -200, nextE = 400;
#pragma unroll
  for (int k = 0; k < 16; ++k) lastE = (yb[k] == 1) ? lastE : (x0 + k);
#pragma unroll
  for (int k = 15; k >= 0; --k) nextE = (yb[k] == 1) ? nextE : (x0 + k);

  __shared__ int lE[8][32];
  __shared__ int nE[8][32];
  lE[c][zl] = lastE;
  nE[c][zl] = nextE;
  __syncthreads();

  int carryL = -200, carryN = 400;
#pragma unroll
  for (int q = 0; q < 7; ++q) {
    if (q < c)     carryL = max(carryL, lE[q][zl]);
    if (q + 1 > c) carryN = min(carryN, nE[q + 1][zl]);
  }

  float yy2f = (float)(yy * yy);
  float hinf = 1000000.f + yy2f;

  int df[16];
  int ll = carryL;
#pragma unroll
  for (int k = 0; k < 16; ++k) {
    ll = (yb[k] == 1) ? ll : (x0 + k);
    df[k] = min(x0 + k - ll, 200);
  }
  float ov[16];
  int nn = carryN;
#pragma unroll
  for (int k = 15; k >= 0; --k) {
    nn = (yb[k] == 1) ? nn : (x0 + k);
    int m = min(df[k], min(nn - (x0 + k), 200));
    ov[k] = (m >= 128) ? hinf : ((float)(m * m) + yy2f);
  }
#pragma unroll
  for (int k = 0; k < 16; ++k) g[base + (size_t)(x0 + k) * 16384] = ov[k];

  float ce = 0.f, ps = 0.f, pts = 0.f, tsum = 0.f;
#pragma unroll
  for (int k = 0; k < 16; ++k) {
    float tt = (yb[k] == 1) ? 1.0f : 0.0f;
    float xx = xv[k];
    ce += fmaxf(xx, 0.0f) - xx * tt + log1pf(expf(-fabsf(xx)));
    float p = 1.0f / (1.0f + expf(-xx));
    ps += p; pts += p * tt; tsum += tt;
  }
  float r0 = wave_redf(ce), r1 = wave_redf(ps), r2 = wave_redf(pts), r3 = wave_redf(tsum);
  __shared__ float sm[4][4];
  int lane = t & 63, w = t >> 6;
  if (lane == 0) { sm[w][0] = r0; sm[w][1] = r1; sm[w][2] = r2; sm[w][3] = r3; }
  __syncthreads();
  if (t == 0) {
    part[blk]        = (double)(sm[0][0] + sm[1][0] + sm[2][0] + sm[3][0]);
    part[1024 + blk] = (double)(sm[0][1] + sm[1][1] + sm[2][1] + sm[3][1]);
    part[2048 + blk] = (double)(sm[0][2] + sm[1][2] + sm[2][2] + sm[3][2]);
    part[3072 + blk] = (double)(sm[0][3] + sm[1][3] + sm[2][3] + sm[3][3]);
  }
}

// ---------------------------------------------------------------------------
// kCD: fused Y+Z windowed-exact EDT + dist loss, one block per (b,x) slab.
// Why fusion is safe NOW (vs round-6 failure): windowed math cut per-pass
// compute 8x, so the kernel is staging-bound; and the exact fallback keeps
// ALL its data because the full slab lives in LDS:
//   hl[144][129]  rows 0..7 & 136..143 = 1e9 pads (y-halo, then z-halo)
//   stage:  hl[y+8][z]   = h            (pitch 129 odd -> <=2-way banks)
//   Y pass: windowed over y rows, per-thread 2x16 outputs; full-slab
//           fallback if bound check fails (exactness certificate, round 8).
//   barrier (all reads done) -> write dY + z^2 TRANSPOSED: hl[z+8][y]
//           (in-place; pad rows never overwritten -> become z-halo).
//   Z pass: windowed over z rows, col y; full fallback available.
// Eliminates dY global write + re-read (33.6 MB) and one launch gap.
// __launch_bounds__(512,1): VGPR cap 256, no spill (round-5 lesson).
// dvy[2][16] statically indexed via unrolled cb loop (rule: no runtime idx).
// ---------------------------------------------------------------------------
__global__ __launch_bounds__(512, 1) void kCD(const float* __restrict__ g,
                                              const float* __restrict__ od,
                                              double* __restrict__ part) {
  __shared__ float hl[144 * 129];   // 74.3 KB
  __shared__ float sred[8];
  int blk = blockIdx.x;             // b*128 + xx
  int b = blk >> 7, xx = blk & 127;
  int t = threadIdx.x;
  size_t rb = (size_t)b * M_SPATIAL + (size_t)xx * 16384;

  // Pad rows (8 bottom, 8 top) with a value that can never win.
  for (int idx = t; idx < 8 * 129; idx += 512) {
    hl[idx] = 1.0e9f;
    hl[136 * 129 + idx] = 1.0e9f;
  }
  // Stage the slab: 4096 float4 coalesced reads, 4 scalar LDS writes each.
  const float4* g4 = (const float4*)(g + rb);
#pragma unroll
  for (int r = 0; r < 8; ++r) {
    int i4 = t + r * 512;           // 0..4095
    float4 v = g4[i4];
    int yy = i4 >> 5, z4 = (i4 & 31) * 4;
    float* p = &hl[(yy + 8) * 129 + z4];
    p[0] = v.x; p[1] = v.y; p[2] = v.z; p[3] = v.w;
  }
  __syncthreads();

  // ---- Y pass: thread (z = t&127, ig = t>>7), 2 chunks x 16 y-outputs.
  int zcol = t & 127, ig = t >> 7;
  float dvy[2][16];
#pragma unroll
  for (int cb = 0; cb < 2; ++cb) {
    int ibase = ig * 32 + cb * 16;
    float best[16], mc[16];
#pragma unroll
    for (int k = 0; k < 16; ++k) {
      best[k] = 3.0e38f;
      mc[k] = -2.0f * (float)(ibase + k);
    }
    float jb = (float)(ibase - 8);
#pragma unroll 4
    for (int p = 0; p < 16; ++p) {     // rows [ibase, ibase+32) = yj+8
      float h0 = hl[(ibase + 2 * p) * 129 + zcol];
      float h1 = hl[(ibase + 2 * p + 1) * 129 + zcol];
      float j0 = jb + (float)(2 * p), j1 = jb + (float)(2 * p + 1);
#pragma unroll
      for (int k = 0; k < 16; ++k) {
        float v0 = fmaf(mc[k], j0, h0);
        float v1 = fmaf(mc[k], j1, h1);
        best[k] = min3f(v0, v1, best[k]);
      }
    }
    int ok = 1;
#pragma unroll
    for (int k = 0; k < 16; ++k) {
      int i = ibase + k;
      dvy[cb][k] = (float)(i * i) + best[k];
      float bnd = (float)min((k + 9) * (k + 9), (24 - k) * (24 - k));
      ok &= (dvy[cb][k] <= bnd);
    }
    if (!__all(ok)) {                   // exactness not certified -> full scan
#pragma unroll
      for (int k = 0; k < 16; ++k) best[k] = 3.0e38f;
#pragma unroll 2
      for (int j = 0; j < 128; j += 2) {
        float h0 = hl[(j + 8) * 129 + zcol];
        float h1 = hl[(j + 9) * 129 + zcol];
        float j0 = (float)j, j1 = (float)(j + 1);
#pragma unroll
        for (int k = 0; k < 16; ++k) {
          float v0 = fmaf(mc[k], j0, h0);
          float v1 = fmaf(mc[k], j1, h1);
          best[k] = min3f(v0, v1, best[k]);
        }
      }
#pragma unroll
      for (int k = 0; k < 16; ++k) {
        int i = ibase + k;
        dvy[cb][k] = (float)(i * i) + best[k];
      }
    }
  }
  __syncthreads();                      // ALL h reads complete
  // Transposed in-place write: hl[z+8][y] = dY^2 + z^2 (payload for Z pass).
  {
    float zq = (float)(zcol * zcol);
#pragma unroll
    for (int cb = 0; cb < 2; ++cb) {
      int ibase = ig * 32 + cb * 16;
#pragma unroll
      for (int k = 0; k < 16; ++k)
        hl[(zcol + 8) * 129 + (ibase + k)] = dvy[cb][k] + zq;
    }
  }
  __syncthreads();

  // ---- Z pass + dist: thread (y = t&127, izg = t>>7), 2 chunks x 16 z.
  int ycol = t & 127, izg = t >> 7;
  // od prefetch: this thread's 32 consecutive z (coalesced float4).
  size_t odb = (size_t)(2 * b + 1) * M_SPATIAL + (size_t)xx * 16384 +
               (size_t)ycol * 128 + (size_t)izg * 32;
  const float4* o4 = (const float4*)(od + odb);
  float4 ovv[8];
#pragma unroll
  for (int r = 0; r < 8; ++r) ovv[r] = o4[r];
  const float* of = (const float*)ovv;

  float dist = 0.f;
#pragma unroll
  for (int cb = 0; cb < 2; ++cb) {
    int izb = izg * 32 + cb * 16;
    float best[16], mc[16];
#pragma unroll
    for (int k = 0; k < 16; ++k) {
      best[k] = 3.0e38f;
      mc[k] = -2.0f * (float)(izb + k);
    }
    float jb = (float)(izb - 8);
#pragma unroll 4
    for (int p = 0; p < 16; ++p) {     // rows [izb, izb+32) = zj+8
      float h0 = hl[(izb + 2 * p) * 129 + ycol];
      float h1 = hl[(izb + 2 * p + 1) * 129 + ycol];
      float j0 = jb + (float)(2 * p), j1 = jb + (float)(2 * p + 1);
#pragma unroll
      for (int k = 0; k < 16; ++k) {
        float v0 = fmaf(mc[k], j0, h0);
        float v1 = fmaf(mc[k], j1, h1);
        best[k] = min3f(v0, v1, best[k]);
      }
    }
    float dv[16];
    int ok = 1;
#pragma unroll
    for (int k = 0; k < 16; ++k) {
      int i = izb + k;
      dv[k] = (float)(i * i) + best[k];
      float bnd = (float)min((k + 9) * (k + 9), (24 - k) * (24 - k));
      ok &= (dv[k] <= bnd);
    }
    if (!__all(ok)) {
#pragma unroll
      for (int k = 0; k < 16; ++k) best[k] = 3.0e38f;
#pragma unroll 2
      for (int j = 0; j < 128; j += 2) {
        float h0 = hl[(j + 8) * 129 + ycol];
        float h1 = hl[(j + 9) * 129 + ycol];
        float j0 = (float)j, j1 = (float)(j + 1);
#pragma unroll
        for (int k = 0; k < 16; ++k) {
          float v0 = fmaf(mc[k], j0, h0);
          float v1 = fmaf(mc[k], j1, h1);
          best[k] = min3f(v0, v1, best[k]);
        }
      }
#pragma unroll
      for (int k = 0; k < 16; ++k) {
        int i = izb + k;
        dv[k] = (float)(i * i) + best[k];
      }
    }
#pragma unroll
    for (int k = 0; k < 16; ++k) {
      if (dv[k] > 0.f) dist += fabsf(of[cb * 16 + k] - sqrtf(dv[k]));
    }
  }
  float r = wave_redf(dist);
  int lane = t & 63, w = t >> 6;
  if (lane == 0) sred[w] = r;
  __syncthreads();
  if (t == 0) {
    float s = 0.f;
#pragma unroll
    for (int q = 0; q < 8; ++q) s += sred[q];
    part[4096 + blk] = (double)s;
  }
}

// ---------------------------------------------------------------------------
// k_final: reduce partials (1024 ce/dice slots, 256 dist slots) -> loss.
// ---------------------------------------------------------------------------
__global__ __launch_bounds__(256) void k_final(const double* __restrict__ part,
                                               const float* __restrict__ wptr,
                                               float* __restrict__ out) {
  int i = threadIdx.x;
  double ce  = part[i] + part[i + 256] + part[i + 512] + part[i + 768];
  double p0  = part[1024 + i] + part[1024 + i + 256];
  double p1  = part[1536 + i] + part[1536 + i + 256];
  double pt0 = part[2048 + i] + part[2048 + i + 256];
  double pt1 = part[2560 + i] + part[2560 + i + 256];
  double t0  = part[3072 + i] + part[3072 + i + 256];
  double t1  = part[3584 + i] + part[3584 + i + 256];
  double ds  = part[4096 + i];   // 256 kCD blocks, one slot per thread

  ce = wave_redd(ce); p0 = wave_redd(p0); p1 = wave_redd(p1);
  pt0 = wave_redd(pt0); pt1 = wave_redd(pt1);
  t0 = wave_redd(t0); t1 = wave_redd(t1); ds = wave_redd(ds);

  __shared__ double sm[4][8];
  int lane = threadIdx.x & 63, w = threadIdx.x >> 6;
  if (lane == 0) {
    sm[w][0] = ce; sm[w][1] = p0; sm[w][2] = p1; sm[w][3] = pt0;
    sm[w][4] = pt1; sm[w][5] = t0; sm[w][6] = t1; sm[w][7] = ds;
  }
  __syncthreads();
  if (threadIdx.x == 0) {
    double a[8];
    for (int q = 0; q < 8; ++q) a[q] = sm[0][q] + sm[1][q] + sm[2][q] + sm[3][q];
    double cem = a[0] / 4194304.0;
    double dice0 = (2.0 * a[3] + 1.0) / (a[1] + a[5] + 1.0);
    double dice1 = (2.0 * a[4] + 1.0) / (a[2] + a[6] + 1.0);
    double ldice = 1.0 - 0.5 * (dice0 + dice1);
    double msum = a[5] + a[6];
    double ldist = (msum == 0.0) ? 0.0 : a[7] / fmax(msum, 1e-12);
    out[0] = (float)(cem + ldice + (double)wptr[0] * ldist);
  }
}

extern "C" void kernel_launch(void* const* d_in, const int* in_sizes, int n_in,
                              void* d_out, int out_size, void* d_ws, size_t ws_size,
                              hipStream_t stream) {
  const float* outputs      = (const float*)d_in[0];
  const float* outputs_dist = (const float*)d_in[1];
  const int*   y            = (const int*)d_in[2];
  const float* wptr         = (const float*)d_in[3];
  float* out = (float*)d_out;

  double* part = (double*)d_ws;                    // 4352 doubles
  float* g = (float*)((char*)d_ws + 65536);        // 16 MiB h field

  kAB<<<1024, 256, 0, stream>>>(y, outputs, g, part);      // X + CE/dice
  kCD<<<256, 512, 0, stream>>>(g, outputs_dist, part);     // fused Y+Z + dist
  k_final<<<1, 256, 0, stream>>>(part, wptr, out);
}